// Round 12
// baseline (129.742 us; speedup 1.0000x reference)
//
#include <hip/hip_runtime.h>
#include <math.h>

#define NPTS 8192
#define DIM 32
#define TILE 128
#define NT (NPTS / TILE)              // 64 tiles per side
#define NTP (NT * (NT + 1) / 2)       // 2080 upper-tri tile pairs
#define NBINS 4096
#define BIN_SCALE 20.0f               // bins per unit d^2
#define NR 16
#define NBLK 1024                     // 4 blocks/CU (38KB LDS x4 <= 160KB)
#define LROW 40                       // shorts per LDS panel row (80 B padded)
#define REP 8                         // attribution: x8 all bins == same slope

using bf16x8 = __attribute__((ext_vector_type(8))) short;
using f32x4  = __attribute__((ext_vector_type(4))) float;

__device__ __forceinline__ unsigned short f2bf(float f) {
    unsigned u = __float_as_uint(f);
    return (unsigned short)((u + 0x7fffu + ((u >> 16) & 1u)) >> 16);
}

// ------- kernel 0: fp32 -> bf16 + 20*norms + zero cnt ---------------------
__global__ void k_prep(const float* __restrict__ pts, unsigned* __restrict__ bp,
                       float* __restrict__ sq20, unsigned* __restrict__ cnt) {
    const int t = blockIdx.x * 256 + threadIdx.x;   // 0..16383
    if (t < NBINS) cnt[t] = 0u;                     // replaces hipMemsetAsync
    const int p = t >> 1, h = t & 1;
    const float4* src = (const float4*)(pts + (size_t)p * DIM + h * 16);
    const float4 v0 = src[0], v1 = src[1], v2 = src[2], v3 = src[3];
    float s = v0.x * v0.x + v0.y * v0.y + v0.z * v0.z + v0.w * v0.w
            + v1.x * v1.x + v1.y * v1.y + v1.z * v1.z + v1.w * v1.w
            + v2.x * v2.x + v2.y * v2.y + v2.z * v2.z + v2.w * v2.w
            + v3.x * v3.x + v3.y * v3.y + v3.z * v3.z + v3.w * v3.w;
    s += __shfl_xor(s, 1);
    if (!h) sq20[p] = s * BIN_SCALE;                // pre-scaled norms
    unsigned* dst = bp + (size_t)p * 16 + h * 8;    // 8 uints = 16 bf16
    dst[0] = (unsigned)f2bf(v0.x) | ((unsigned)f2bf(v0.y) << 16);
    dst[1] = (unsigned)f2bf(v0.z) | ((unsigned)f2bf(v0.w) << 16);
    dst[2] = (unsigned)f2bf(v1.x) | ((unsigned)f2bf(v1.y) << 16);
    dst[3] = (unsigned)f2bf(v1.z) | ((unsigned)f2bf(v1.w) << 16);
    dst[4] = (unsigned)f2bf(v2.x) | ((unsigned)f2bf(v2.y) << 16);
    dst[5] = (unsigned)f2bf(v2.z) | ((unsigned)f2bf(v2.w) << 16);
    dst[6] = (unsigned)f2bf(v3.x) | ((unsigned)f2bf(v3.y) << 16);
    dst[7] = (unsigned)f2bf(v3.z) | ((unsigned)f2bf(v3.w) << 16);
}

// ------- kernel 1: MFMA gram + d^2 histogram ------------------------------
// One mfma_f32_16x16x32_bf16 = one full 16x16 gram block (DIM==K==32);
// acc consumed immediately (r1-r5 lesson: no long-lived accumulator state).
// REP outer loop multiplies every bin count by REP -- slope-invariant --
// to lift k_hist above the 39us fill floor for rocprof attribution.

#define EPI1(ACC, SA20, GROW, DIAGQ) { \
    const float bf_ = fmaf(-40.f, ACC, (SA20) + sb20); \
    const int bin_ = (int)fminf(fmaxf(bf_, 0.f), (float)(NBINS - 1)); \
    if (!(DIAGQ) || ((GROW) < gcol)) atomicAdd(&hist[bin_], 1u); }

#define TCLOOP(DIAGQ) \
    _Pragma("unroll") \
    for (int tc = 0; tc < 8; ++tc) { \
        const bf16x8 bf = *(const bf16x8*)&Bb[(tc * 16 + l15) * LROW + lc * 8]; \
        const f32x4 z = {0.f, 0.f, 0.f, 0.f}; \
        const f32x4 d0 = __builtin_amdgcn_mfma_f32_16x16x32_bf16(a0, bf, z, 0, 0, 0); \
        const f32x4 d1 = __builtin_amdgcn_mfma_f32_16x16x32_bf16(a1, bf, z, 0, 0, 0); \
        const float sb20 = sqb[tc * 16 + l15]; \
        const int gcol = tj * TILE + tc * 16 + l15; (void)gcol; \
        EPI1(d0[0], sa00, g0 + 0, DIAGQ) EPI1(d0[1], sa01, g0 + 1, DIAGQ) \
        EPI1(d0[2], sa02, g0 + 2, DIAGQ) EPI1(d0[3], sa03, g0 + 3, DIAGQ) \
        EPI1(d1[0], sa10, g1 + 0, DIAGQ) EPI1(d1[1], sa11, g1 + 1, DIAGQ) \
        EPI1(d1[2], sa12, g1 + 2, DIAGQ) EPI1(d1[3], sa13, g1 + 3, DIAGQ) \
    }

__global__ __launch_bounds__(256)
void k_hist(const uint4* __restrict__ bp4, const float* __restrict__ sq20,
            unsigned* __restrict__ cnt) {
    __shared__ unsigned hist[NBINS];                 // 16 KB
    __shared__ unsigned short Ab[TILE * LROW];       // 10 KB
    __shared__ unsigned short Bb[TILE * LROW];       // 10 KB
    __shared__ float sqa[TILE], sqb[TILE];           // 1 KB (pre-scaled by 20)
    const int tid = threadIdx.x;
    const int lane = tid & 63, w = tid >> 6;
    const int l15 = lane & 15, lc = lane >> 4;       // col-in-tile, k-chunk
    for (int b = tid; b < NBINS; b += 256) hist[b] = 0u;
    const int P = gridDim.x;

    for (int rep = 0; rep < REP; ++rep) {
    for (int tp = blockIdx.x; tp < NTP; tp += P) {
        int ti = 0, rr = tp;
        while (rr >= NT - ti) { rr -= NT - ti; ++ti; }
        const int tj = ti + rr;

        __syncthreads();   // prior iteration's reads + atomics done
#pragma unroll
        for (int q = 0; q < 2; ++q) {
            const int g = tid + q * 256;             // 0..511
            const int p = g >> 2, c = g & 3;
            *(uint4*)&Ab[p * LROW + c * 8] = bp4[(size_t)ti * 512 + g];
            *(uint4*)&Bb[p * LROW + c * 8] = bp4[(size_t)tj * 512 + g];
        }
        if (tid < TILE) sqa[tid] = sq20[ti * TILE + tid];
        else if (tid < 2 * TILE) sqb[tid - TILE] = sq20[tj * TILE + (tid - TILE)];
        __syncthreads();

        const int r0 = (2 * w) * 16, r1 = r0 + 16;   // this wave's tile-rows
        const bf16x8 a0 = *(const bf16x8*)&Ab[(r0 + l15) * LROW + lc * 8];
        const bf16x8 a1 = *(const bf16x8*)&Ab[(r1 + l15) * LROW + lc * 8];
        const float sa00 = sqa[r0 + lc * 4 + 0];
        const float sa01 = sqa[r0 + lc * 4 + 1];
        const float sa02 = sqa[r0 + lc * 4 + 2];
        const float sa03 = sqa[r0 + lc * 4 + 3];
        const float sa10 = sqa[r1 + lc * 4 + 0];
        const float sa11 = sqa[r1 + lc * 4 + 1];
        const float sa12 = sqa[r1 + lc * 4 + 2];
        const float sa13 = sqa[r1 + lc * 4 + 3];
        const int g0 = ti * TILE + r0 + lc * 4;      // + j  = global row
        const int g1 = ti * TILE + r1 + lc * 4;

        if (ti != tj) {
            TCLOOP(0)
        } else {
            TCLOOP(1)
        }
    }
    }

    __syncthreads();
    for (int b = tid; b < NBINS; b += 256) {
        const unsigned h = hist[b];
        if (h) atomicAdd(&cnt[b], h);                // device-scope, deterministic
    }
}

// ------- kernel 2: sigmoid sums + regression (single block) ---------------
// Thread-0 tail uses HW v_log_f32 (logf) instead of software f64 log:
// y = logf(sums)-logf(cnt) in f32, f64 elsewhere. Err ~1e-6 << 0.33.
__global__ __launch_bounds__(1024)
void k_final(const unsigned* __restrict__ cnt, const float* __restrict__ rvals,
             float* __restrict__ out) {
    __shared__ double red[16][NR + 1];               // per-wave partials
    const int tid = threadIdx.x;
    float rv[NR];
#pragma unroll
    for (int t = 0; t < NR; ++t) rv[t] = rvals[t];

    double local[NR + 1];
#pragma unroll
    for (int t = 0; t <= NR; ++t) local[t] = 0.0;

#pragma unroll
    for (int q = 0; q < NBINS / 1024; ++q) {
        const int b = tid + q * 1024;
        const unsigned c = cnt[b];
        if (c) {
            const double cd = (double)c;
            local[NR] += cd;
            const float d = sqrtf(((float)b + 0.5f) / BIN_SCALE);
#pragma unroll
            for (int t = 0; t < NR; ++t) {
                const float x = 10.0f * (rv[t] - d);
                float s;
                if (x >= 0.f) s = 1.f / (1.f + __expf(-x));
                else          { const float e = __expf(x); s = e / (1.f + e); }
                local[t] += cd * (double)s;
            }
        }
    }

#pragma unroll
    for (int off = 32; off > 0; off >>= 1) {
#pragma unroll
        for (int t = 0; t <= NR; ++t)
            local[t] += __shfl_down(local[t], off);
    }
    const int wv = tid >> 6;
    if ((tid & 63) == 0) {
#pragma unroll
        for (int t = 0; t <= NR; ++t) red[wv][t] = local[t];
    }
    __syncthreads();

    if (tid == 0) {
        double sums[NR + 1];
#pragma unroll
        for (int t = 0; t <= NR; ++t) {
            double s = 0.0;
#pragma unroll
            for (int w2 = 0; w2 < 16; ++w2) s += red[w2][t];
            sums[t] = s;
        }
        const float logC = logf((float)sums[NR]);
        double Sx = 0, Sy = 0, Sxx = 0, Sxy = 0;
#pragma unroll
        for (int t = 0; t < NR; ++t) {
            const double x = (double)logf(rv[t]);
            const double y = (double)(logf((float)sums[t]) - logC);
            Sx += x; Sy += y; Sxx += x * x; Sxy += x * y;
        }
        const double R = (double)NR;
        const double slope = (R * Sxy - Sx * Sy) / (R * Sxx - Sx * Sx);
        out[0] = (float)(-slope);
    }
}

extern "C" void kernel_launch(void* const* d_in, const int* in_sizes, int n_in,
                              void* d_out, int out_size, void* d_ws, size_t ws_size,
                              hipStream_t stream) {
    const float* pts = (const float*)d_in[0];
    const float* rv  = (const float*)d_in[1];
    float* out = (float*)d_out;
    char* ws = (char*)d_ws;

    unsigned* bp = (unsigned*)ws;                     // 512 KB bf16 points
    float* sq20 = (float*)(ws + 524288);              // 32 KB scaled norms
    unsigned* cnt = (unsigned*)(ws + 524288 + 32768); // 16 KB global hist

    k_prep<<<64, 256, 0, stream>>>(pts, bp, sq20, cnt);
    k_hist<<<NBLK, 256, 0, stream>>>((const uint4*)bp, sq20, cnt);
    k_final<<<1, 1024, 0, stream>>>(cnt, rv, out);
}

// Round 13
// 57.566 us; speedup vs baseline: 2.2538x; 2.2538x over previous
//
#include <hip/hip_runtime.h>
#include <math.h>

#define NPTS 8192
#define DIM 32
#define TILE 128
#define NT (NPTS / TILE)              // 64 tiles per side
#define NTP (NT * (NT + 1) / 2)       // 2080 upper-tri tile pairs
#define NBINS 4096
#define BIN_SCALE 20.0f               // bins per unit d^2
#define NR 16
#define NBLK 1024                     // 4 blocks/CU
#define LROW 40                       // shorts per LDS panel row (80 B padded)

using bf16x8 = __attribute__((ext_vector_type(8))) short;
using f32x4  = __attribute__((ext_vector_type(4))) float;

__device__ __forceinline__ unsigned short f2bf(float f) {
    unsigned u = __float_as_uint(f);
    return (unsigned short)((u + 0x7fffu + ((u >> 16) & 1u)) >> 16);
}

// ------- kernel 0: fp32 -> bf16 + 20*norms + zero cnt ---------------------
__global__ void k_prep(const float* __restrict__ pts, unsigned* __restrict__ bp,
                       float* __restrict__ sq20, unsigned* __restrict__ cnt) {
    const int t = blockIdx.x * 256 + threadIdx.x;   // 0..16383
    if (t < NBINS) cnt[t] = 0u;                     // replaces hipMemsetAsync
    const int p = t >> 1, h = t & 1;
    const float4* src = (const float4*)(pts + (size_t)p * DIM + h * 16);
    const float4 v0 = src[0], v1 = src[1], v2 = src[2], v3 = src[3];
    float s = v0.x * v0.x + v0.y * v0.y + v0.z * v0.z + v0.w * v0.w
            + v1.x * v1.x + v1.y * v1.y + v1.z * v1.z + v1.w * v1.w
            + v2.x * v2.x + v2.y * v2.y + v2.z * v2.z + v2.w * v2.w
            + v3.x * v3.x + v3.y * v3.y + v3.z * v3.z + v3.w * v3.w;
    s += __shfl_xor(s, 1);
    if (!h) sq20[p] = s * BIN_SCALE;                // pre-scaled norms
    unsigned* dst = bp + (size_t)p * 16 + h * 8;    // 8 uints = 16 bf16
    dst[0] = (unsigned)f2bf(v0.x) | ((unsigned)f2bf(v0.y) << 16);
    dst[1] = (unsigned)f2bf(v0.z) | ((unsigned)f2bf(v0.w) << 16);
    dst[2] = (unsigned)f2bf(v1.x) | ((unsigned)f2bf(v1.y) << 16);
    dst[3] = (unsigned)f2bf(v1.z) | ((unsigned)f2bf(v1.w) << 16);
    dst[4] = (unsigned)f2bf(v2.x) | ((unsigned)f2bf(v2.y) << 16);
    dst[5] = (unsigned)f2bf(v2.z) | ((unsigned)f2bf(v2.w) << 16);
    dst[6] = (unsigned)f2bf(v3.x) | ((unsigned)f2bf(v3.y) << 16);
    dst[7] = (unsigned)f2bf(v3.z) | ((unsigned)f2bf(v3.w) << 16);
}

// ------- kernel 1: MFMA gram + d^2 histogram ------------------------------
// One mfma_f32_16x16x32_bf16 = one full 16x16 gram block (DIM==K==32);
// acc consumed immediately (r1-r5 lesson: no long-lived accumulator state).
// Measured (r12, REP=8): T = 14.1us/pass, VALU 40%, bank-conflict 3.25M/pass.

#define EPI1(ACC, SA20, GROW, DIAGQ) { \
    const float bf_ = fmaf(-40.f, ACC, (SA20) + sb20); \
    const int bin_ = (int)fminf(fmaxf(bf_, 0.f), (float)(NBINS - 1)); \
    if (!(DIAGQ) || ((GROW) < gcol)) atomicAdd(&hist[bin_], 1u); }

#define TCLOOP(DIAGQ) \
    _Pragma("unroll") \
    for (int tc = 0; tc < 8; ++tc) { \
        const bf16x8 bf = *(const bf16x8*)&Bb[(tc * 16 + l15) * LROW + lc * 8]; \
        const f32x4 z = {0.f, 0.f, 0.f, 0.f}; \
        const f32x4 d0 = __builtin_amdgcn_mfma_f32_16x16x32_bf16(a0, bf, z, 0, 0, 0); \
        const f32x4 d1 = __builtin_amdgcn_mfma_f32_16x16x32_bf16(a1, bf, z, 0, 0, 0); \
        const float sb20 = sqb[tc * 16 + l15]; \
        const int gcol = tj * TILE + tc * 16 + l15; (void)gcol; \
        EPI1(d0[0], sa00, g0 + 0, DIAGQ) EPI1(d0[1], sa01, g0 + 1, DIAGQ) \
        EPI1(d0[2], sa02, g0 + 2, DIAGQ) EPI1(d0[3], sa03, g0 + 3, DIAGQ) \
        EPI1(d1[0], sa10, g1 + 0, DIAGQ) EPI1(d1[1], sa11, g1 + 1, DIAGQ) \
        EPI1(d1[2], sa12, g1 + 2, DIAGQ) EPI1(d1[3], sa13, g1 + 3, DIAGQ) \
    }

__global__ __launch_bounds__(256)
void k_hist(const uint4* __restrict__ bp4, const float* __restrict__ sq20,
            unsigned* __restrict__ cnt) {
    __shared__ unsigned hist[NBINS];                 // 16 KB
    __shared__ unsigned short Ab[TILE * LROW];       // 10 KB
    __shared__ unsigned short Bb[TILE * LROW];       // 10 KB
    __shared__ float sqa[TILE], sqb[TILE];           // 1 KB (pre-scaled by 20)
    const int tid = threadIdx.x;
    const int lane = tid & 63, w = tid >> 6;
    const int l15 = lane & 15, lc = lane >> 4;       // col-in-tile, k-chunk
    for (int b = tid; b < NBINS; b += 256) hist[b] = 0u;
    const int P = gridDim.x;

    for (int tp = blockIdx.x; tp < NTP; tp += P) {
        int ti = 0, rr = tp;
        while (rr >= NT - ti) { rr -= NT - ti; ++ti; }
        const int tj = ti + rr;

        __syncthreads();   // prior iteration's reads + atomics done
#pragma unroll
        for (int q = 0; q < 2; ++q) {
            const int g = tid + q * 256;             // 0..511
            const int p = g >> 2, c = g & 3;
            *(uint4*)&Ab[p * LROW + c * 8] = bp4[(size_t)ti * 512 + g];
            *(uint4*)&Bb[p * LROW + c * 8] = bp4[(size_t)tj * 512 + g];
        }
        if (tid < TILE) sqa[tid] = sq20[ti * TILE + tid];
        else if (tid < 2 * TILE) sqb[tid - TILE] = sq20[tj * TILE + (tid - TILE)];
        __syncthreads();

        const int r0 = (2 * w) * 16, r1 = r0 + 16;   // this wave's tile-rows
        const bf16x8 a0 = *(const bf16x8*)&Ab[(r0 + l15) * LROW + lc * 8];
        const bf16x8 a1 = *(const bf16x8*)&Ab[(r1 + l15) * LROW + lc * 8];
        const float sa00 = sqa[r0 + lc * 4 + 0];
        const float sa01 = sqa[r0 + lc * 4 + 1];
        const float sa02 = sqa[r0 + lc * 4 + 2];
        const float sa03 = sqa[r0 + lc * 4 + 3];
        const float sa10 = sqa[r1 + lc * 4 + 0];
        const float sa11 = sqa[r1 + lc * 4 + 1];
        const float sa12 = sqa[r1 + lc * 4 + 2];
        const float sa13 = sqa[r1 + lc * 4 + 3];
        const int g0 = ti * TILE + r0 + lc * 4;      // + j  = global row
        const int g1 = ti * TILE + r1 + lc * 4;

        if (ti != tj) {
            TCLOOP(0)
        } else {
            TCLOOP(1)
        }
    }

    __syncthreads();
    for (int b = tid; b < NBINS; b += 256) {
        const unsigned h = hist[b];
        if (h) atomicAdd(&cnt[b], h);                // device-scope, deterministic
    }
}

// ------- kernel 2: sigmoid sums + regression (single block) ---------------
// Tail uses HW v_log_f32 (logf); the old software-f64 log/div serial tail
// was ~35us on one lane (r12 attribution) -- never reintroduce f64 libm.
__global__ __launch_bounds__(1024)
void k_final(const unsigned* __restrict__ cnt, const float* __restrict__ rvals,
             float* __restrict__ out) {
    __shared__ double red[16][NR + 1];               // per-wave partials
    const int tid = threadIdx.x;
    float rv[NR];
#pragma unroll
    for (int t = 0; t < NR; ++t) rv[t] = rvals[t];

    double local[NR + 1];
#pragma unroll
    for (int t = 0; t <= NR; ++t) local[t] = 0.0;

#pragma unroll
    for (int q = 0; q < NBINS / 1024; ++q) {
        const int b = tid + q * 1024;
        const unsigned c = cnt[b];
        if (c) {
            const double cd = (double)c;
            local[NR] += cd;
            const float d = sqrtf(((float)b + 0.5f) / BIN_SCALE);
#pragma unroll
            for (int t = 0; t < NR; ++t) {
                const float x = 10.0f * (rv[t] - d);
                float s;
                if (x >= 0.f) s = 1.f / (1.f + __expf(-x));
                else          { const float e = __expf(x); s = e / (1.f + e); }
                local[t] += cd * (double)s;
            }
        }
    }

#pragma unroll
    for (int off = 32; off > 0; off >>= 1) {
#pragma unroll
        for (int t = 0; t <= NR; ++t)
            local[t] += __shfl_down(local[t], off);
    }
    const int wv = tid >> 6;
    if ((tid & 63) == 0) {
#pragma unroll
        for (int t = 0; t <= NR; ++t) red[wv][t] = local[t];
    }
    __syncthreads();

    if (tid == 0) {
        double sums[NR + 1];
#pragma unroll
        for (int t = 0; t <= NR; ++t) {
            double s = 0.0;
#pragma unroll
            for (int w2 = 0; w2 < 16; ++w2) s += red[w2][t];
            sums[t] = s;
        }
        const float logC = logf((float)sums[NR]);
        double Sx = 0, Sy = 0, Sxx = 0, Sxy = 0;
#pragma unroll
        for (int t = 0; t < NR; ++t) {
            const double x = (double)logf(rv[t]);
            const double y = (double)(logf((float)sums[t]) - logC);
            Sx += x; Sy += y; Sxx += x * x; Sxy += x * y;
        }
        const double R = (double)NR;
        const double slope = (R * Sxy - Sx * Sy) / (R * Sxx - Sx * Sx);
        out[0] = (float)(-slope);
    }
}

extern "C" void kernel_launch(void* const* d_in, const int* in_sizes, int n_in,
                              void* d_out, int out_size, void* d_ws, size_t ws_size,
                              hipStream_t stream) {
    const float* pts = (const float*)d_in[0];
    const float* rv  = (const float*)d_in[1];
    float* out = (float*)d_out;
    char* ws = (char*)d_ws;

    unsigned* bp = (unsigned*)ws;                     // 512 KB bf16 points
    float* sq20 = (float*)(ws + 524288);              // 32 KB scaled norms
    unsigned* cnt = (unsigned*)(ws + 524288 + 32768); // 16 KB global hist

    k_prep<<<64, 256, 0, stream>>>(pts, bp, sq20, cnt);
    k_hist<<<NBLK, 256, 0, stream>>>((const uint4*)bp, sq20, cnt);
    k_final<<<1, 1024, 0, stream>>>(cnt, rv, out);
}

// Round 14
// 55.320 us; speedup vs baseline: 2.3453x; 1.0406x over previous
//
#include <hip/hip_runtime.h>
#include <math.h>

#define NPTS 8192
#define DIM 32
#define TILE 128
#define NT (NPTS / TILE)              // 64 tiles per side
#define NTP (NT * (NT + 1) / 2)       // 2080 upper-tri tile pairs
#define NBINS 4096
#define BIN_SCALE 20.0f               // bins per unit d^2
#define NR 16
#define NBLK 512                      // halves flush atomics vs 1024 (r9 vs r11)
#define LROW 40                       // shorts per LDS panel row (80 B padded)

using bf16x8 = __attribute__((ext_vector_type(8))) short;
using f32x4  = __attribute__((ext_vector_type(4))) float;

__device__ __forceinline__ unsigned short f2bf(float f) {
    unsigned u = __float_as_uint(f);
    return (unsigned short)((u + 0x7fffu + ((u >> 16) & 1u)) >> 16);
}

// ------- kernel 0: fp32 -> bf16 + 20*norms + zero cnt ---------------------
__global__ void k_prep(const float* __restrict__ pts, unsigned* __restrict__ bp,
                       float* __restrict__ sq20, unsigned* __restrict__ cnt) {
    const int t = blockIdx.x * 256 + threadIdx.x;   // 0..16383
    if (t < NBINS) cnt[t] = 0u;                     // replaces hipMemsetAsync
    const int p = t >> 1, h = t & 1;
    const float4* src = (const float4*)(pts + (size_t)p * DIM + h * 16);
    const float4 v0 = src[0], v1 = src[1], v2 = src[2], v3 = src[3];
    float s = v0.x * v0.x + v0.y * v0.y + v0.z * v0.z + v0.w * v0.w
            + v1.x * v1.x + v1.y * v1.y + v1.z * v1.z + v1.w * v1.w
            + v2.x * v2.x + v2.y * v2.y + v2.z * v2.z + v2.w * v2.w
            + v3.x * v3.x + v3.y * v3.y + v3.z * v3.z + v3.w * v3.w;
    s += __shfl_xor(s, 1);
    if (!h) sq20[p] = s * BIN_SCALE;                // pre-scaled norms
    unsigned* dst = bp + (size_t)p * 16 + h * 8;    // 8 uints = 16 bf16
    dst[0] = (unsigned)f2bf(v0.x) | ((unsigned)f2bf(v0.y) << 16);
    dst[1] = (unsigned)f2bf(v0.z) | ((unsigned)f2bf(v0.w) << 16);
    dst[2] = (unsigned)f2bf(v1.x) | ((unsigned)f2bf(v1.y) << 16);
    dst[3] = (unsigned)f2bf(v1.z) | ((unsigned)f2bf(v1.w) << 16);
    dst[4] = (unsigned)f2bf(v2.x) | ((unsigned)f2bf(v2.y) << 16);
    dst[5] = (unsigned)f2bf(v2.z) | ((unsigned)f2bf(v2.w) << 16);
    dst[6] = (unsigned)f2bf(v3.x) | ((unsigned)f2bf(v3.y) << 16);
    dst[7] = (unsigned)f2bf(v3.z) | ((unsigned)f2bf(v3.w) << 16);
}

// ------- kernel 1: MFMA gram + d^2 histogram ------------------------------
// One mfma_f32_16x16x32_bf16 = one full 16x16 gram block (DIM==K==32);
// acc consumed immediately (r1-r5 lesson). LDS-atomic-pipe bound (r12/r13
// attribution: ~10.5us in-graph, VALU 40%). 2-way sub-histogram by wave
// parity halves same-address atomic serialization (d^2 distribution is
// concentrated, sigma ~640 bins -> frequent same-bin hits across waves).

#define EPI1(ACC, SA20, GROW, DIAGQ) { \
    const float bf_ = fmaf(-40.f, ACC, (SA20) + sb20); \
    const int bin_ = (int)fminf(fmaxf(bf_, 0.f), (float)(NBINS - 1)); \
    if (!(DIAGQ) || ((GROW) < gcol)) atomicAdd(&myh[bin_], 1u); }

#define TCLOOP(DIAGQ) \
    _Pragma("unroll") \
    for (int tc = 0; tc < 8; ++tc) { \
        const bf16x8 bf = *(const bf16x8*)&Bb[(tc * 16 + l15) * LROW + lc * 8]; \
        const f32x4 z = {0.f, 0.f, 0.f, 0.f}; \
        const f32x4 d0 = __builtin_amdgcn_mfma_f32_16x16x32_bf16(a0, bf, z, 0, 0, 0); \
        const f32x4 d1 = __builtin_amdgcn_mfma_f32_16x16x32_bf16(a1, bf, z, 0, 0, 0); \
        const float sb20 = sqb[tc * 16 + l15]; \
        const int gcol = tj * TILE + tc * 16 + l15; (void)gcol; \
        EPI1(d0[0], sa00, g0 + 0, DIAGQ) EPI1(d0[1], sa01, g0 + 1, DIAGQ) \
        EPI1(d0[2], sa02, g0 + 2, DIAGQ) EPI1(d0[3], sa03, g0 + 3, DIAGQ) \
        EPI1(d1[0], sa10, g1 + 0, DIAGQ) EPI1(d1[1], sa11, g1 + 1, DIAGQ) \
        EPI1(d1[2], sa12, g1 + 2, DIAGQ) EPI1(d1[3], sa13, g1 + 3, DIAGQ) \
    }

__global__ __launch_bounds__(256)
void k_hist(const uint4* __restrict__ bp4, const float* __restrict__ sq20,
            unsigned* __restrict__ cnt) {
    __shared__ unsigned hist[2 * NBINS];             // 32 KB (2 sub-hists)
    __shared__ unsigned short Ab[TILE * LROW];       // 10 KB
    __shared__ unsigned short Bb[TILE * LROW];       // 10 KB
    __shared__ float sqa[TILE], sqb[TILE];           // 1 KB (pre-scaled by 20)
    const int tid = threadIdx.x;
    const int lane = tid & 63, w = tid >> 6;
    const int l15 = lane & 15, lc = lane >> 4;       // col-in-tile, k-chunk
    unsigned* myh = hist + ((w & 1) << 12);          // wave-parity sub-hist
    for (int b = tid; b < 2 * NBINS; b += 256) hist[b] = 0u;
    const int P = gridDim.x;

    for (int tp = blockIdx.x; tp < NTP; tp += P) {
        int ti = 0, rr = tp;
        while (rr >= NT - ti) { rr -= NT - ti; ++ti; }
        const int tj = ti + rr;

        __syncthreads();   // prior iteration's reads + atomics done
#pragma unroll
        for (int q = 0; q < 2; ++q) {
            const int g = tid + q * 256;             // 0..511
            const int p = g >> 2, c = g & 3;
            *(uint4*)&Ab[p * LROW + c * 8] = bp4[(size_t)ti * 512 + g];
            *(uint4*)&Bb[p * LROW + c * 8] = bp4[(size_t)tj * 512 + g];
        }
        if (tid < TILE) sqa[tid] = sq20[ti * TILE + tid];
        else if (tid < 2 * TILE) sqb[tid - TILE] = sq20[tj * TILE + (tid - TILE)];
        __syncthreads();

        const int r0 = (2 * w) * 16, r1 = r0 + 16;   // this wave's tile-rows
        const bf16x8 a0 = *(const bf16x8*)&Ab[(r0 + l15) * LROW + lc * 8];
        const bf16x8 a1 = *(const bf16x8*)&Ab[(r1 + l15) * LROW + lc * 8];
        const float sa00 = sqa[r0 + lc * 4 + 0];
        const float sa01 = sqa[r0 + lc * 4 + 1];
        const float sa02 = sqa[r0 + lc * 4 + 2];
        const float sa03 = sqa[r0 + lc * 4 + 3];
        const float sa10 = sqa[r1 + lc * 4 + 0];
        const float sa11 = sqa[r1 + lc * 4 + 1];
        const float sa12 = sqa[r1 + lc * 4 + 2];
        const float sa13 = sqa[r1 + lc * 4 + 3];
        const int g0 = ti * TILE + r0 + lc * 4;      // + j  = global row
        const int g1 = ti * TILE + r1 + lc * 4;

        if (ti != tj) {
            TCLOOP(0)
        } else {
            TCLOOP(1)
        }
    }

    __syncthreads();
    for (int b = tid; b < NBINS; b += 256) {
        const unsigned h = hist[b] + hist[b + NBINS];
        if (h) atomicAdd(&cnt[b], h);                // device-scope, deterministic
    }
}

// ------- kernel 2: sigmoid sums + regression (single block) ---------------
// Tail uses HW v_log_f32 (logf); the old software-f64 log tail cost ~5us
// serial on one lane (r11 vs r13) -- never reintroduce f64 libm.
__global__ __launch_bounds__(1024)
void k_final(const unsigned* __restrict__ cnt, const float* __restrict__ rvals,
             float* __restrict__ out) {
    __shared__ double red[16][NR + 1];               // per-wave partials
    const int tid = threadIdx.x;
    float rv[NR];
#pragma unroll
    for (int t = 0; t < NR; ++t) rv[t] = rvals[t];

    double local[NR + 1];
#pragma unroll
    for (int t = 0; t <= NR; ++t) local[t] = 0.0;

#pragma unroll
    for (int q = 0; q < NBINS / 1024; ++q) {
        const int b = tid + q * 1024;
        const unsigned c = cnt[b];
        if (c) {
            const double cd = (double)c;
            local[NR] += cd;
            const float d = sqrtf(((float)b + 0.5f) / BIN_SCALE);
#pragma unroll
            for (int t = 0; t < NR; ++t) {
                const float x = 10.0f * (rv[t] - d);
                float s;
                if (x >= 0.f) s = 1.f / (1.f + __expf(-x));
                else          { const float e = __expf(x); s = e / (1.f + e); }
                local[t] += cd * (double)s;
            }
        }
    }

#pragma unroll
    for (int off = 32; off > 0; off >>= 1) {
#pragma unroll
        for (int t = 0; t <= NR; ++t)
            local[t] += __shfl_down(local[t], off);
    }
    const int wv = tid >> 6;
    if ((tid & 63) == 0) {
#pragma unroll
        for (int t = 0; t <= NR; ++t) red[wv][t] = local[t];
    }
    __syncthreads();

    if (tid == 0) {
        double sums[NR + 1];
#pragma unroll
        for (int t = 0; t <= NR; ++t) {
            double s = 0.0;
#pragma unroll
            for (int w2 = 0; w2 < 16; ++w2) s += red[w2][t];
            sums[t] = s;
        }
        const float logC = logf((float)sums[NR]);
        double Sx = 0, Sy = 0, Sxx = 0, Sxy = 0;
#pragma unroll
        for (int t = 0; t < NR; ++t) {
            const double x = (double)logf(rv[t]);
            const double y = (double)(logf((float)sums[t]) - logC);
            Sx += x; Sy += y; Sxx += x * x; Sxy += x * y;
        }
        const double R = (double)NR;
        const double slope = (R * Sxy - Sx * Sy) / (R * Sxx - Sx * Sx);
        out[0] = (float)(-slope);
    }
}

extern "C" void kernel_launch(void* const* d_in, const int* in_sizes, int n_in,
                              void* d_out, int out_size, void* d_ws, size_t ws_size,
                              hipStream_t stream) {
    const float* pts = (const float*)d_in[0];
    const float* rv  = (const float*)d_in[1];
    float* out = (float*)d_out;
    char* ws = (char*)d_ws;

    unsigned* bp = (unsigned*)ws;                     // 512 KB bf16 points
    float* sq20 = (float*)(ws + 524288);              // 32 KB scaled norms
    unsigned* cnt = (unsigned*)(ws + 524288 + 32768); // 16 KB global hist

    k_prep<<<64, 256, 0, stream>>>(pts, bp, sq20, cnt);
    k_hist<<<NBLK, 256, 0, stream>>>((const uint4*)bp, sq20, cnt);
    k_final<<<1, 1024, 0, stream>>>(cnt, rv, out);
}

// Round 15
// 51.993 us; speedup vs baseline: 2.4954x; 1.0640x over previous
//
#include <hip/hip_runtime.h>
#include <math.h>

#define NPTS 8192
#define DIM 32
#define TILE 128
#define NT (NPTS / TILE)              // 64 tiles per side
#define NTP (NT * (NT + 1) / 2)       // 2080 upper-tri tile pairs
#define NBINS 4096
#define BIN_SCALE 20.0f               // bins per unit d^2
#define NR 16
#define NBLK 256                      // 1 block/CU (141KB LDS)
#define NSUB 8                        // bin-interleaved sub-hists (lane&7)
#define LROW 40                       // shorts per LDS panel row (80 B padded)

using bf16x8 = __attribute__((ext_vector_type(8))) short;
using f32x4  = __attribute__((ext_vector_type(4))) float;

__device__ __forceinline__ unsigned short f2bf(float f) {
    unsigned u = __float_as_uint(f);
    return (unsigned short)((u + 0x7fffu + ((u >> 16) & 1u)) >> 16);
}

__device__ __forceinline__ void tp_decode(int tp, int& ti, int& tj) {
    int t = 0, r = tp;
    while (r >= NT - t) { r -= NT - t; ++t; }
    ti = t; tj = t + r;
}

// ------- kernel 0: fp32 -> bf16 + 20*norms + zero cnt ---------------------
__global__ void k_prep(const float* __restrict__ pts, unsigned* __restrict__ bp,
                       float* __restrict__ sq20, unsigned* __restrict__ cnt) {
    const int t = blockIdx.x * 256 + threadIdx.x;   // 0..16383
    if (t < NBINS) cnt[t] = 0u;                     // replaces hipMemsetAsync
    const int p = t >> 1, h = t & 1;
    const float4* src = (const float4*)(pts + (size_t)p * DIM + h * 16);
    const float4 v0 = src[0], v1 = src[1], v2 = src[2], v3 = src[3];
    float s = v0.x * v0.x + v0.y * v0.y + v0.z * v0.z + v0.w * v0.w
            + v1.x * v1.x + v1.y * v1.y + v1.z * v1.z + v1.w * v1.w
            + v2.x * v2.x + v2.y * v2.y + v2.z * v2.z + v2.w * v2.w
            + v3.x * v3.x + v3.y * v3.y + v3.z * v3.z + v3.w * v3.w;
    s += __shfl_xor(s, 1);
    if (!h) sq20[p] = s * BIN_SCALE;                // pre-scaled norms
    unsigned* dst = bp + (size_t)p * 16 + h * 8;    // 8 uints = 16 bf16
    dst[0] = (unsigned)f2bf(v0.x) | ((unsigned)f2bf(v0.y) << 16);
    dst[1] = (unsigned)f2bf(v0.z) | ((unsigned)f2bf(v0.w) << 16);
    dst[2] = (unsigned)f2bf(v1.x) | ((unsigned)f2bf(v1.y) << 16);
    dst[3] = (unsigned)f2bf(v1.z) | ((unsigned)f2bf(v1.w) << 16);
    dst[4] = (unsigned)f2bf(v2.x) | ((unsigned)f2bf(v2.y) << 16);
    dst[5] = (unsigned)f2bf(v2.z) | ((unsigned)f2bf(v2.w) << 16);
    dst[6] = (unsigned)f2bf(v3.x) | ((unsigned)f2bf(v3.y) << 16);
    dst[7] = (unsigned)f2bf(v3.z) | ((unsigned)f2bf(v3.w) << 16);
}

// ------- kernel 1: MFMA gram + d^2 histogram ------------------------------
// 512 thr = 8 waves, each owning one 16-row block of the 128x128 tile.
// Bin-interleaved 8-way sub-hist: idx = bin*8 + (lane&7) -> same-bin lanes
// land in 8 consecutive banks (no intra-wave same-address/same-bank atomic
// serialization; r12 measured 3.25M conflict-cycles/pass on single hist).
// A-frags + norms read direct from global (L2-resident, coalesced);
// B panel register-prefetched one tile ahead (hides L2 latency at 1 blk/CU).

#define EPI1(ACC, SA20, GROW, DIAGQ) { \
    const float bf_ = fmaf(-40.f, ACC, (SA20) + sb20); \
    const int bin_ = (int)fminf(fmaxf(bf_, 0.f), (float)(NBINS - 1)); \
    if (!(DIAGQ) || ((GROW) < gcol)) atomicAdd(&hist[(bin_ << 3) + sub], 1u); }

#define TCLOOP(DIAGQ) \
    _Pragma("unroll") \
    for (int tc = 0; tc < 8; ++tc) { \
        const bf16x8 bf = *(const bf16x8*)&Bb[(tc * 16 + l15) * LROW + lc * 8]; \
        const f32x4 z = {0.f, 0.f, 0.f, 0.f}; \
        const f32x4 d0 = __builtin_amdgcn_mfma_f32_16x16x32_bf16(a0, bf, z, 0, 0, 0); \
        const float sb20 = sq20[ctj * TILE + tc * 16 + l15]; \
        const int gcol = ctj * TILE + tc * 16 + l15; (void)gcol; \
        EPI1(d0[0], sa0, g0 + 0, DIAGQ) EPI1(d0[1], sa1, g0 + 1, DIAGQ) \
        EPI1(d0[2], sa2, g0 + 2, DIAGQ) EPI1(d0[3], sa3, g0 + 3, DIAGQ) \
    }

__global__ __launch_bounds__(512)
void k_hist(const uint4* __restrict__ bp4, const float* __restrict__ sq20,
            unsigned* __restrict__ cnt) {
    __shared__ unsigned hist[NBINS * NSUB];          // 128 KB, bin-interleaved
    __shared__ unsigned short Bb[TILE * LROW];       // 10 KB
    const int tid = threadIdx.x;
    const int lane = tid & 63, w = tid >> 6;         // 8 waves
    const int l15 = lane & 15, lc = lane >> 4;       // col-in-tile, k-chunk
    const int sub = lane & 7;                        // sub-hist slot
    {   // zero hist: 16 uint4 stores per thread
        uint4* h4 = (uint4*)hist;
        const uint4 z4 = {0u, 0u, 0u, 0u};
        for (int i = tid; i < NBINS * NSUB / 4; i += 512) h4[i] = z4;
    }
    const int P = gridDim.x;
    const bf16x8* bpv = (const bf16x8*)bp4;

    int tp = blockIdx.x;
    int ti, tj;
    tp_decode(tp, ti, tj);
    uint4 reg = bp4[(size_t)tj * 512 + tid];         // prefetch first B panel

    while (tp < NTP) {
        __syncthreads();                             // Bb free (prev compute done)
        {   const int p = tid >> 2, c = tid & 3;
            *(uint4*)&Bb[p * LROW + c * 8] = reg; }
        __syncthreads();                             // Bb ready
        const int cti = ti, ctj = tj;
        tp += P;
        if (tp < NTP) {                              // issue next panel early
            tp_decode(tp, ti, tj);
            reg = bp4[(size_t)tj * 512 + tid];
        }

        const int base_a = cti * TILE + w * 16;      // this wave's row block
        const bf16x8 a0 = bpv[(size_t)(base_a + l15) * 4 + lc];
        const float sa0 = sq20[base_a + lc * 4 + 0];
        const float sa1 = sq20[base_a + lc * 4 + 1];
        const float sa2 = sq20[base_a + lc * 4 + 2];
        const float sa3 = sq20[base_a + lc * 4 + 3];
        const int g0 = base_a + lc * 4;              // + j = global row

        if (cti != ctj) {
            TCLOOP(0)
        } else {
            TCLOOP(1)
        }
    }

    __syncthreads();
    for (int b = tid; b < NBINS; b += 512) {         // sum 8 slots, one atomic
        const uint4 h0 = *(const uint4*)&hist[b * 8];
        const uint4 h1 = *(const uint4*)&hist[b * 8 + 4];
        const unsigned h = h0.x + h0.y + h0.z + h0.w + h1.x + h1.y + h1.z + h1.w;
        if (h) atomicAdd(&cnt[b], h);                // device-scope, deterministic
    }
}

// ------- kernel 2: sigmoid sums + regression (single block) ---------------
// f32 __expf / logf only; software-f64 libm in the tail cost ~5us serial
// (r11 vs r13) -- never reintroduce.
__global__ __launch_bounds__(1024)
void k_final(const unsigned* __restrict__ cnt, const float* __restrict__ rvals,
             float* __restrict__ out) {
    __shared__ double red[16][NR + 1];               // per-wave partials
    const int tid = threadIdx.x;
    float rv[NR];
#pragma unroll
    for (int t = 0; t < NR; ++t) rv[t] = rvals[t];

    double local[NR + 1];
#pragma unroll
    for (int t = 0; t <= NR; ++t) local[t] = 0.0;

#pragma unroll
    for (int q = 0; q < NBINS / 1024; ++q) {
        const int b = tid + q * 1024;
        const unsigned c = cnt[b];
        if (c) {
            const double cd = (double)c;
            local[NR] += cd;
            const float d = sqrtf(((float)b + 0.5f) / BIN_SCALE);
#pragma unroll
            for (int t = 0; t < NR; ++t) {
                const float x = 10.0f * (rv[t] - d);
                float s;
                if (x >= 0.f) s = 1.f / (1.f + __expf(-x));
                else          { const float e = __expf(x); s = e / (1.f + e); }
                local[t] += cd * (double)s;
            }
        }
    }

#pragma unroll
    for (int off = 32; off > 0; off >>= 1) {
#pragma unroll
        for (int t = 0; t <= NR; ++t)
            local[t] += __shfl_down(local[t], off);
    }
    const int wv = tid >> 6;
    if ((tid & 63) == 0) {
#pragma unroll
        for (int t = 0; t <= NR; ++t) red[wv][t] = local[t];
    }
    __syncthreads();

    if (tid == 0) {
        double sums[NR + 1];
#pragma unroll
        for (int t = 0; t <= NR; ++t) {
            double s = 0.0;
#pragma unroll
            for (int w2 = 0; w2 < 16; ++w2) s += red[w2][t];
            sums[t] = s;
        }
        const float logC = logf((float)sums[NR]);
        double Sx = 0, Sy = 0, Sxx = 0, Sxy = 0;
#pragma unroll
        for (int t = 0; t < NR; ++t) {
            const double x = (double)logf(rv[t]);
            const double y = (double)(logf((float)sums[t]) - logC);
            Sx += x; Sy += y; Sxx += x * x; Sxy += x * y;
        }
        const double R = (double)NR;
        const double slope = (R * Sxy - Sx * Sy) / (R * Sxx - Sx * Sx);
        out[0] = (float)(-slope);
    }
}

extern "C" void kernel_launch(void* const* d_in, const int* in_sizes, int n_in,
                              void* d_out, int out_size, void* d_ws, size_t ws_size,
                              hipStream_t stream) {
    const float* pts = (const float*)d_in[0];
    const float* rv  = (const float*)d_in[1];
    float* out = (float*)d_out;
    char* ws = (char*)d_ws;

    unsigned* bp = (unsigned*)ws;                     // 512 KB bf16 points
    float* sq20 = (float*)(ws + 524288);              // 32 KB scaled norms
    unsigned* cnt = (unsigned*)(ws + 524288 + 32768); // 16 KB global hist

    k_prep<<<64, 256, 0, stream>>>(pts, bp, sq20, cnt);
    k_hist<<<NBLK, 512, 0, stream>>>((const uint4*)bp, sq20, cnt);
    k_final<<<1, 1024, 0, stream>>>(cnt, rv, out);
}